// Round 22
// baseline (183.347 us; speedup 1.0000x reference)
//
#include <hip/hip_runtime.h>
#include <stdint.h>

using u16 = unsigned short;
using u32 = unsigned int;
using u64 = unsigned long long;

typedef float f32x4 __attribute__((ext_vector_type(4)));
typedef __bf16 bf16x8 __attribute__((ext_vector_type(8)));

#define DEV static __device__ __forceinline__

// f32 -> bf16 round-to-nearest-even
DEV u16 f2bf(float f) {
  u32 u = __float_as_uint(f);
  u += 0x7FFFu + ((u >> 16) & 1u);
  return (u16)(u >> 16);
}

// async global->LDS, 16B per lane. LDS dest = wave-uniform base + lane*16.
DEV void gld16(const void* g, void* l) {
  __builtin_amdgcn_global_load_lds((__attribute__((address_space(1))) void*)g,
                                   (__attribute__((address_space(3))) void*)l,
                                   16, 0, 0);
}

// ---------------------------------------------------------------- converts
// merged: blocks [0,2048) convert x (f32->bf16); blocks [2048,3072) convert+
// transpose the four weight matrices.
__global__ void k_cvt(const float* __restrict__ x, u16* __restrict__ xb,
                      const float* __restrict__ w0, const float* __restrict__ w1,
                      const float* __restrict__ w2, const float* __restrict__ w3,
                      u16* __restrict__ t0, u16* __restrict__ t1,
                      u16* __restrict__ t2, u16* __restrict__ t3) {
  const int tid = threadIdx.x;
  if (blockIdx.x < 2048) {
    int i = (blockIdx.x * 256 + tid) * 8;
    float4 a = *(const float4*)&x[i];
    float4 b = *(const float4*)&x[i + 4];
    __align__(16) u16 o[8];
    o[0] = f2bf(a.x); o[1] = f2bf(a.y); o[2] = f2bf(a.z); o[3] = f2bf(a.w);
    o[4] = f2bf(b.x); o[5] = f2bf(b.y); o[6] = f2bf(b.z); o[7] = f2bf(b.w);
    *(uint4*)&xb[i] = *(const uint4*)o;
    return;
  }
  const int c = blockIdx.x - 2048;
  const int z = c >> 8, rem = c & 255;
  const float* w = z == 0 ? w0 : z == 1 ? w1 : z == 2 ? w2 : w3;
  u16* wt       = z == 0 ? t0 : z == 1 ? t1 : z == 2 ? t2 : t3;
  __shared__ __align__(16) float tile[64][68];
  const int k0 = (rem & 15) * 64, n0 = (rem >> 4) * 64;
#pragma unroll
  for (int i = 0; i < 4; ++i) {
    int cc = tid + i * 256;         // 1024 float4 chunks
    int kr = cc >> 4, col = (cc & 15) * 4;
    *(float4*)&tile[kr][col] = *(const float4*)&w[(size_t)(k0 + kr) * 1024 + n0 + col];
  }
  __syncthreads();
#pragma unroll
  for (int i = 0; i < 2; ++i) {
    int cc = tid + i * 256;         // 512 8xu16 chunks
    int nr = cc >> 3, kc = (cc & 7) * 8;
    __align__(16) u16 o[8];
#pragma unroll
    for (int j = 0; j < 8; ++j) o[j] = f2bf(tile[kc + j][nr]);
    *(uint4*)&wt[(size_t)(n0 + nr) * 1024 + k0 + kc] = *(const uint4*)o;
  }
}

// ---------------------------------------------------------------- GEMM core
// 8-wave (512-thread) counted-vmcnt pipeline: 3 LDS buffers, depth-2
// prefetch, ONE raw s_barrier per K-step, vmcnt(2) steady. Wave grid 2x4
// over the 128x128 tile: each wave owns 64x32 (acc[4][2]).
DEV void gemm8_mainloop(const u16* __restrict__ A, const u16* __restrict__ Bt,
                        int m0, int n0, u16* Asb, u16* Bsb, f32x4 (&acc)[4][2]) {
  const int tid = threadIdx.x;
  const int lane = tid & 63;
  const int lo = lane & 15, hi = lane >> 4;
  const int wv = tid >> 6;
  const int wm = (wv >> 2) * 64, wn = (wv & 3) * 32;

#pragma unroll
  for (int f = 0; f < 4; ++f)
#pragma unroll
    for (int g = 0; g < 2; ++g) {
      f32x4 z = {0.f, 0.f, 0.f, 0.f};
      acc[f][g] = z;
    }

  // staging: 512 chunks of 16B per 128x32 tile; chunk = tid
  const int r = tid >> 2;
  const int bblk = (tid & 3) ^ (r & 3) ^ ((r >> 2) & 3);
  const u16* ga = A + (size_t)(m0 + r) * 1024 + bblk * 8;
  const u16* gb = Bt + (size_t)(n0 + r) * 1024 + bblk * 8;
  const int dst = wv * 512;        // wave-uniform chunk-group base (u16 idx)

  int aoff[4], boff[2];
#pragma unroll
  for (int f = 0; f < 4; ++f) {
    int ra = wm + f * 16 + lo;
    aoff[f] = ra * 32 + ((hi ^ (ra & 3) ^ ((ra >> 2) & 3)) * 8);
  }
#pragma unroll
  for (int g = 0; g < 2; ++g) {
    int rb = wn + g * 16 + lo;
    boff[g] = rb * 32 + ((hi ^ (rb & 3) ^ ((rb >> 2) & 3)) * 8);
  }

  // prologue: stage kt=0 -> buf0, kt=1 -> buf1 (4 VMEM ops outstanding/wave)
#pragma unroll
  for (int p = 0; p < 2; ++p) {
    const int k0 = p * 32, bo = p * 4096;
    gld16(ga + k0, Asb + bo + dst);
    gld16(gb + k0, Bsb + bo + dst);
  }

#pragma unroll 1
  for (int kt = 0; kt < 32; ++kt) {
    if (kt < 31) asm volatile("s_waitcnt vmcnt(2)" ::: "memory");
    else         asm volatile("s_waitcnt vmcnt(0)" ::: "memory");
    __builtin_amdgcn_s_barrier();
    __builtin_amdgcn_sched_barrier(0);

    if (kt + 2 < 32) {
      const int k0 = (kt + 2) * 32, bo = ((kt + 2) % 3) * 4096;
      gld16(ga + k0, Asb + bo + dst);
      gld16(gb + k0, Bsb + bo + dst);
    }

    const int bo = (kt % 3) * 4096;
    bf16x8 af[4], bf[2];
#pragma unroll
    for (int f = 0; f < 4; ++f) af[f] = *(const bf16x8*)&Asb[bo + aoff[f]];
#pragma unroll
    for (int g = 0; g < 2; ++g) bf[g] = *(const bf16x8*)&Bsb[bo + boff[g]];
#pragma unroll
    for (int f = 0; f < 4; ++f)
#pragma unroll
      for (int g = 0; g < 2; ++g)
        acc[f][g] = __builtin_amdgcn_mfma_f32_16x16x32_bf16(af[f], bf[g], acc[f][g], 0, 0, 0);
  }
}

// fused QKV projection: X[4096][1024]bf16 * Wt[1024][1024] -> Q/K [32][2048][64]
// bf16, and V directly into Vt' [32][64][2048] (transposed + sigma-permuted)
// via an LDS round-trip. 512 threads, 8 waves -> 6 waves/SIMD at 3 blocks/CU.
__global__ __launch_bounds__(512, 6) void k_gemm_qkv(
    const u16* __restrict__ X, const u16* __restrict__ Wq, const u16* __restrict__ Wk,
    const u16* __restrict__ Wv, u16* __restrict__ Q, u16* __restrict__ K,
    u16* __restrict__ Vt) {
  __shared__ __align__(16) u16 SH[24576];      // 48KB: staging, then C-tile
  u16* Asb = SH;
  u16* Bsb = SH + 12288;
  const int nb = blockIdx.x, mb = blockIdx.y;
  const int proj = nb >> 3, n0 = (nb & 7) * 128;
  const u16* W = proj == 0 ? Wq : proj == 1 ? Wk : Wv;
  // fold 1/sqrt(64) * log2(e) into Q so attention can use exp2 directly
  const float scl = proj == 0 ? 0.125f * 1.4426950408889634f : 1.0f;
  f32x4 acc[4][2];
  gemm8_mainloop(X, W, mb * 128, n0, Asb, Bsb, acc);

  const int tid = threadIdx.x;
  const int lane = tid & 63, wv = tid >> 6;
  const int lo = lane & 15, hi = lane >> 4;
  const int wm = (wv >> 2) * 64, wn = (wv & 3) * 32;
  const int b = (mb * 128) >> 11;              // tile never crosses batch
  const int sbase = (mb * 128) & 2047;
  const int h0 = n0 >> 6;

  // all waves done reading staging LDS before we overwrite it with C
  __syncthreads();

  if (proj == 2) {
    // V: TRANSPOSED C-tile in LDS: Ctv[n_local][s_local], padded [128][132]
    u16 (*Ctv)[132] = (u16(*)[132])SH;
#pragma unroll
    for (int f = 0; f < 4; ++f)
#pragma unroll
      for (int g = 0; g < 2; ++g)
#pragma unroll
        for (int rr = 0; rr < 4; ++rr)
          Ctv[wn + g * 16 + lo][wm + f * 16 + hi * 4 + rr] = f2bf(acc[f][g][rr]);
    __syncthreads();
    // sigma write: dst offset bp(g2) covers one full 128B line per 16 lanes
    const int g2 = tid & 15;
    const int bp = ((g2 >> 2) & 1) * 32 + ((g2 >> 1) & 1) * 16 + (g2 & 1) * 8 +
                   ((g2 >> 3) & 1) * 4;
#pragma unroll
    for (int p = 0; p < 8; ++p) {
      const int ci = p * 32 + (tid >> 4);      // 0..255
      const int blk = ci & 1, d = (ci >> 1) & 63, hl = ci >> 7;
      u64 v = *(const u64*)&Ctv[hl * 64 + d][blk * 64 + g2 * 4];
      *(u64*)&Vt[((size_t)((b * 16 + h0 + hl) * 64 + d)) * 2048 +
                 sbase + blk * 64 + bp] = v;
    }
  } else {
    u16* Dst = proj == 0 ? Q : K;
    u16 (*Ct)[132] = (u16(*)[132])SH;          // [128][132] padded, 33KB
#pragma unroll
    for (int f = 0; f < 4; ++f)
#pragma unroll
      for (int g = 0; g < 2; ++g)
#pragma unroll
        for (int rr = 0; rr < 4; ++rr)
          Ct[wm + f * 16 + hi * 4 + rr][wn + g * 16 + lo] = f2bf(acc[f][g][rr] * scl);
    __syncthreads();
    // coalesced out: 4 passes x (32 rows x 16 chunks of 8 u16)
#pragma unroll
    for (int p = 0; p < 4; ++p) {
      const int row = p * 32 + (tid >> 4);
      const int ch = tid & 15;
      const int h = h0 + (ch >> 3), d = (ch & 7) * 8;
      __align__(16) u16 o[8];
#pragma unroll
      for (int q = 0; q < 8; ++q) o[q] = Ct[row][ch * 8 + q];
      *(uint4*)&Dst[(size_t)((b * 16 + h) * 2048 + sbase + row) * 64 + d] = *(const uint4*)o;
    }
  }
}

// output projection: AO[4096][1024]bf16 * WOt -> f32 out [4096][1024].
// 512 threads, 2 waves/SIMD at the 1-block/CU grid. Epilogue goes through a
// 2-half f32 LDS round-trip so global writes are pure float4 full-line
// streams.
__global__ __launch_bounds__(512, 2) void k_gemm_out(
    const u16* __restrict__ A, const u16* __restrict__ Wt, float* __restrict__ Out) {
  __shared__ __align__(16) u16 SH[24576];      // 48KB: staging, then C halves
  u16* Asb = SH;
  u16* Bsb = SH + 12288;
  const int nb = blockIdx.x, mb = blockIdx.y;
  f32x4 acc[4][2];
  gemm8_mainloop(A, Wt, mb * 128, nb * 128, Asb, Bsb, acc);
  const int tid = threadIdx.x;
  const int lane = tid & 63, wv = tid >> 6;
  const int lo = lane & 15, hi = lane >> 4;
  const int wm = (wv >> 2) * 64, wn = (wv & 3) * 32;

  float (*Cf)[132] = (float(*)[132])SH;        // [64][132] f32, 33.8KB
#pragma unroll 1
  for (int hl = 0; hl < 2; ++hl) {
    __syncthreads();   // staging reads (hl=0) / previous half's stores (hl=1) done
    if (wm == hl * 64) {
#pragma unroll
      for (int f = 0; f < 4; ++f)
#pragma unroll
        for (int g = 0; g < 2; ++g)
#pragma unroll
          for (int rr = 0; rr < 4; ++rr)
            Cf[f * 16 + hi * 4 + rr][wn + g * 16 + lo] = acc[f][g][rr];
    }
    __syncthreads();
    // 64 rows x 32 float4 chunks = 2048 chunks; 4 per thread, coalesced
#pragma unroll
    for (int p = 0; p < 4; ++p) {
      const int c = p * 512 + tid;
      const int row = c >> 5, col4 = (c & 31) * 4;
      float4 v = *(const float4*)&Cf[row][col4];
      *(float4*)&Out[(size_t)(mb * 128 + hl * 64 + row) * 1024 + nb * 128 + col4] = v;
    }
  }
}

// ---------------------------------------------------------------- attention
// DIRECT-L2 VARIANT: K/V per XCD-group (2MB) is L2-resident, so LDS staging
// is pure overhead (guide common-mistake #7). Each wave reads its K/V
// fragments straight from global into registers: NO LDS, NO barriers, NO
// manual waitcnt — the compiler tracks register deps and inserts counted
// vmcnt waits. V loads issue before the softmax chain so their latency hides
// under it. Waves free-run; A-group exits at its causal extent (no idle
// barrier iterations). Per-block work = 132 wave-tiles for every jp.
__global__ __launch_bounds__(512, 4) void k_attn(
    const u16* __restrict__ Qg, const u16* __restrict__ Kg,
    const u16* __restrict__ Vtg, u16* __restrict__ Og) {
  const int tid = threadIdx.x, lane = tid & 63, wv = tid >> 6;
  const int lo = lane & 15, hi = lane >> 4;
  const int w4 = wv & 3, qsel = wv >> 2;

  const int flat = blockIdx.y * 16 + blockIdx.x;
  const int xcd = flat & 7, slot = flat >> 3;       // 64 slots per XCD
  const int q4 = slot >> 4, rsl = slot & 15;
  const int bh = xcd * 4 + q4;                      // 4 bh per XCD
  const int jp = (q4 & 2) ? (15 - rsl) : rsl;       // complementary pairing

  const u16* Qb = Qg + (size_t)bh * 2048 * 64;
  const u16* Kb = Kg + (size_t)bh * 2048 * 64;
  const u16* Vb = Vtg + (size_t)bh * 64 * 2048;
  const int b = bh >> 4, h = bh & 15;

  const int q0 = (qsel ? (31 - jp) : jp) * 64;
  const int myNt = qsel ? (32 - jp) : (jp + 1);     // my causal extent
  const int qq = q0 + w4 * 16 + lo;

  // Q fragments (scale * log2e folded in); B-operand of swapped QK^T
  bf16x8 qf[2];
#pragma unroll
  for (int kf = 0; kf < 2; ++kf)
    qf[kf] = *(const bf16x8*)&Qb[(size_t)(q0 + w4 * 16 + lo) * 64 + kf * 32 + hi * 8];

  f32x4 ao[4];
#pragma unroll
  for (int df = 0; df < 4; ++df) {
    f32x4 z = {0.f, 0.f, 0.f, 0.f};
    ao[df] = z;
  }
  float m_run = -1e30f, l_run = 0.f;

#pragma unroll 1
  for (int t = 0; t < myNt; ++t) {
    const int kv0 = t * 64;

    // K fragments: K[kv0+cf*16+lo][(kf*4+hi)*8 ..+8] (8 x dwordx4 from L2)
    bf16x8 kfr[4][2];
#pragma unroll
    for (int cf = 0; cf < 4; ++cf)
#pragma unroll
      for (int kf = 0; kf < 2; ++kf)
        kfr[cf][kf] = *(const bf16x8*)&Kb[(size_t)(kv0 + cf * 16 + lo) * 64 +
                                          (kf * 4 + hi) * 8];
    // V fragments issued NOW so their L2 latency hides under QK + softmax
    bf16x8 vfr[4][2];
#pragma unroll
    for (int df = 0; df < 4; ++df)
#pragma unroll
      for (int kf = 0; kf < 2; ++kf)
        vfr[df][kf] = *(const bf16x8*)&Vb[(size_t)(df * 16 + lo) * 2048 + kv0 +
                                          (kf * 4 + hi) * 8];

    // swapped QK^T: lane q-row = q0+w4*16+lo, k = kv0+cf*16+hi*4+r
    f32x4 sc[4];
    __builtin_amdgcn_s_setprio(1);
#pragma unroll
    for (int cf = 0; cf < 4; ++cf) {
      f32x4 z = {0.f, 0.f, 0.f, 0.f};
      sc[cf] = z;
#pragma unroll
      for (int kf = 0; kf < 2; ++kf)
        sc[cf] = __builtin_amdgcn_mfma_f32_16x16x32_bf16(kfr[cf][kf], qf[kf],
                                                         sc[cf], 0, 0, 0);
    }
    __builtin_amdgcn_s_setprio(0);

    // causal mask: only this q-tile's diagonal (last) tile
    if (t == myNt - 1) {
#pragma unroll
      for (int cf = 0; cf < 4; ++cf)
#pragma unroll
        for (int r = 0; r < 4; ++r) {
          int kk = kv0 + cf * 16 + hi * 4 + r;
          if (kk > qq) sc[cf][r] = -1e30f;
        }
    }

    // in-lane row max + 2 shuffles
    float mx0 = fmaxf(fmaxf(sc[0][0], sc[0][1]), fmaxf(sc[0][2], sc[0][3]));
    float mx1 = fmaxf(fmaxf(sc[1][0], sc[1][1]), fmaxf(sc[1][2], sc[1][3]));
    float mx2 = fmaxf(fmaxf(sc[2][0], sc[2][1]), fmaxf(sc[2][2], sc[2][3]));
    float mx3 = fmaxf(fmaxf(sc[3][0], sc[3][1]), fmaxf(sc[3][2], sc[3][3]));
    float mx = fmaxf(fmaxf(mx0, mx1), fmaxf(mx2, mx3));
    mx = fmaxf(mx, __shfl_xor(mx, 16));
    mx = fmaxf(mx, __shfl_xor(mx, 32));

    // defer-max: rescale only when the max grew by > 8 (log2 units)
    if (__any(mx > m_run + 8.0f)) {
      float mnew = fmaxf(m_run, mx);
      float sclf = __builtin_amdgcn_exp2f(m_run - mnew);
      const int base = lane & 48;
#pragma unroll
      for (int r = 0; r < 4; ++r) {
        float s_r = __shfl(sclf, base + hi * 4 + r);
#pragma unroll
        for (int df = 0; df < 4; ++df) ao[df][r] *= s_r;
      }
      l_run *= sclf;
      m_run = mnew;
    }

    // P = exp2(sc - m_run), packed in-register into PV A-fragments (sigma)
    float pp[4];
    bf16x8 pa0, pa1;
#pragma unroll
    for (int cf = 0; cf < 4; ++cf) {
      float p0 = __builtin_amdgcn_exp2f(sc[cf][0] - m_run);
      float p1 = __builtin_amdgcn_exp2f(sc[cf][1] - m_run);
      float p2 = __builtin_amdgcn_exp2f(sc[cf][2] - m_run);
      float p3 = __builtin_amdgcn_exp2f(sc[cf][3] - m_run);
      pp[cf] = (p0 + p1) + (p2 + p3);
      bf16x8& pa = (cf & 1) ? pa1 : pa0;
      int j = (cf >> 1) * 4;
      pa[j] = (__bf16)p0; pa[j + 1] = (__bf16)p1;
      pa[j + 2] = (__bf16)p2; pa[j + 3] = (__bf16)p3;
    }
    l_run += (pp[0] + pp[1]) + (pp[2] + pp[3]);   // per-lane partial

    __builtin_amdgcn_s_setprio(1);
#pragma unroll
    for (int df = 0; df < 4; ++df) {
#pragma unroll
      for (int kf = 0; kf < 2; ++kf)
        ao[df] = __builtin_amdgcn_mfma_f32_16x16x32_bf16(kf == 0 ? pa0 : pa1,
                                                         vfr[df][kf], ao[df], 0, 0, 0);
    }
    __builtin_amdgcn_s_setprio(0);
  }

  // epilogue: deferred cross-lane l reduction, then per-row 1/l via shuffle.
  float l_tot = l_run;
  l_tot += __shfl_xor(l_tot, 16);
  l_tot += __shfl_xor(l_tot, 32);
  float linv[4];
  const int base = lane & 48;
#pragma unroll
  for (int r = 0; r < 4; ++r) {
    float l_r = __shfl(l_tot, base + hi * 4 + r);
    linv[r] = 1.0f / l_r;
  }
#pragma unroll
  for (int df = 0; df < 4; ++df)
#pragma unroll
    for (int r = 0; r < 4; ++r) {
      int s = q0 + w4 * 16 + hi * 4 + r;
      int d = df * 16 + lo;
      Og[((size_t)(b * 2048 + s)) * 1024 + h * 64 + d] = f2bf(ao[df][r] * linv[r]);
    }
}

// ---------------------------------------------------------------- launch
extern "C" void kernel_launch(void* const* d_in, const int* in_sizes, int n_in,
                              void* d_out, int out_size, void* d_ws, size_t ws_size,
                              hipStream_t stream) {
  const float* x = (const float*)d_in[0];
  const float* wq = (const float*)d_in[2];
  const float* wk = (const float*)d_in[3];
  const float* wv = (const float*)d_in[4];
  const float* wo = (const float*)d_in[5];

  char* ws = (char*)d_ws;
  u16* xb  = (u16*)(ws);                                   // 8 MiB  x bf16 [4096][1024]
  u16* wqt = (u16*)(ws + 8388608);                         // 2 MiB each, [N][K] bf16
  u16* wkt = (u16*)(ws + 8388608 + 2097152);
  u16* wvt = (u16*)(ws + 8388608 + 2 * 2097152);
  u16* wot = (u16*)(ws + 8388608 + 3 * 2097152);
  u16* qb  = (u16*)(ws + 16777216);                        // [32][2048][64] bf16
  u16* kb  = (u16*)(ws + 16777216 + 8388608);
  u16* vt  = (u16*)(ws + 16777216 + 3 * 8388608);          // [32][64][2048] (sigma-permuted)
  u16* ao  = (u16*)(ws + 16777216 + 4 * 8388608);          // [4096][1024] bf16

  k_cvt<<<dim3(3072), dim3(256), 0, stream>>>(x, xb, wq, wk, wv, wo, wqt, wkt, wvt, wot);
  k_gemm_qkv<<<dim3(24, 32), dim3(512), 0, stream>>>(xb, wqt, wkt, wvt, qb, kb, vt);
  k_attn<<<dim3(16, 32), dim3(512), 0, stream>>>(qb, kb, vt, ao);
  k_gemm_out<<<dim3(8, 32), dim3(512), 0, stream>>>(ao, wot, (float*)d_out);
}

// Round 23
// 103.572 us; speedup vs baseline: 1.7702x; 1.7702x over previous
//
#include <hip/hip_runtime.h>
#include <stdint.h>

using u16 = unsigned short;
using u32 = unsigned int;
using u64 = unsigned long long;

typedef float f32x4 __attribute__((ext_vector_type(4)));
typedef __bf16 bf16x8 __attribute__((ext_vector_type(8)));

#define DEV static __device__ __forceinline__

// f32 -> bf16 round-to-nearest-even
DEV u16 f2bf(float f) {
  u32 u = __float_as_uint(f);
  u += 0x7FFFu + ((u >> 16) & 1u);
  return (u16)(u >> 16);
}

// async global->LDS, 16B per lane. LDS dest = wave-uniform base + lane*16.
DEV void gld16(const void* g, void* l) {
  __builtin_amdgcn_global_load_lds((__attribute__((address_space(1))) void*)g,
                                   (__attribute__((address_space(3))) void*)l,
                                   16, 0, 0);
}

// ---------------------------------------------------------------- converts
// merged: blocks [0,2048) convert x (f32->bf16); blocks [2048,3072) convert+
// transpose the four weight matrices.
__global__ void k_cvt(const float* __restrict__ x, u16* __restrict__ xb,
                      const float* __restrict__ w0, const float* __restrict__ w1,
                      const float* __restrict__ w2, const float* __restrict__ w3,
                      u16* __restrict__ t0, u16* __restrict__ t1,
                      u16* __restrict__ t2, u16* __restrict__ t3) {
  const int tid = threadIdx.x;
  if (blockIdx.x < 2048) {
    int i = (blockIdx.x * 256 + tid) * 8;
    float4 a = *(const float4*)&x[i];
    float4 b = *(const float4*)&x[i + 4];
    __align__(16) u16 o[8];
    o[0] = f2bf(a.x); o[1] = f2bf(a.y); o[2] = f2bf(a.z); o[3] = f2bf(a.w);
    o[4] = f2bf(b.x); o[5] = f2bf(b.y); o[6] = f2bf(b.z); o[7] = f2bf(b.w);
    *(uint4*)&xb[i] = *(const uint4*)o;
    return;
  }
  const int c = blockIdx.x - 2048;
  const int z = c >> 8, rem = c & 255;
  const float* w = z == 0 ? w0 : z == 1 ? w1 : z == 2 ? w2 : w3;
  u16* wt       = z == 0 ? t0 : z == 1 ? t1 : z == 2 ? t2 : t3;
  __shared__ __align__(16) float tile[64][68];
  const int k0 = (rem & 15) * 64, n0 = (rem >> 4) * 64;
#pragma unroll
  for (int i = 0; i < 4; ++i) {
    int cc = tid + i * 256;         // 1024 float4 chunks
    int kr = cc >> 4, col = (cc & 15) * 4;
    *(float4*)&tile[kr][col] = *(const float4*)&w[(size_t)(k0 + kr) * 1024 + n0 + col];
  }
  __syncthreads();
#pragma unroll
  for (int i = 0; i < 2; ++i) {
    int cc = tid + i * 256;         // 512 8xu16 chunks
    int nr = cc >> 3, kc = (cc & 7) * 8;
    __align__(16) u16 o[8];
#pragma unroll
    for (int j = 0; j < 8; ++j) o[j] = f2bf(tile[kc + j][nr]);
    *(uint4*)&wt[(size_t)(n0 + nr) * 1024 + k0 + kc] = *(const uint4*)o;
  }
}

// ---------------------------------------------------------------- GEMM core
// 8-wave (512-thread) counted-vmcnt pipeline: 3 LDS buffers, depth-2
// prefetch, ONE raw s_barrier per K-step, vmcnt(2) steady. Wave grid 2x4
// over the 128x128 tile: each wave owns 64x32 (acc[4][2]).
DEV void gemm8_mainloop(const u16* __restrict__ A, const u16* __restrict__ Bt,
                        int m0, int n0, u16* Asb, u16* Bsb, f32x4 (&acc)[4][2]) {
  const int tid = threadIdx.x;
  const int lane = tid & 63;
  const int lo = lane & 15, hi = lane >> 4;
  const int wv = tid >> 6;
  const int wm = (wv >> 2) * 64, wn = (wv & 3) * 32;

#pragma unroll
  for (int f = 0; f < 4; ++f)
#pragma unroll
    for (int g = 0; g < 2; ++g) {
      f32x4 z = {0.f, 0.f, 0.f, 0.f};
      acc[f][g] = z;
    }

  // staging: 512 chunks of 16B per 128x32 tile; chunk = tid
  const int r = tid >> 2;
  const int bblk = (tid & 3) ^ (r & 3) ^ ((r >> 2) & 3);
  const u16* ga = A + (size_t)(m0 + r) * 1024 + bblk * 8;
  const u16* gb = Bt + (size_t)(n0 + r) * 1024 + bblk * 8;
  const int dst = wv * 512;        // wave-uniform chunk-group base (u16 idx)

  int aoff[4], boff[2];
#pragma unroll
  for (int f = 0; f < 4; ++f) {
    int ra = wm + f * 16 + lo;
    aoff[f] = ra * 32 + ((hi ^ (ra & 3) ^ ((ra >> 2) & 3)) * 8);
  }
#pragma unroll
  for (int g = 0; g < 2; ++g) {
    int rb = wn + g * 16 + lo;
    boff[g] = rb * 32 + ((hi ^ (rb & 3) ^ ((rb >> 2) & 3)) * 8);
  }

  // prologue: stage kt=0 -> buf0, kt=1 -> buf1 (4 VMEM ops outstanding/wave)
#pragma unroll
  for (int p = 0; p < 2; ++p) {
    const int k0 = p * 32, bo = p * 4096;
    gld16(ga + k0, Asb + bo + dst);
    gld16(gb + k0, Bsb + bo + dst);
  }

#pragma unroll 1
  for (int kt = 0; kt < 32; ++kt) {
    if (kt < 31) asm volatile("s_waitcnt vmcnt(2)" ::: "memory");
    else         asm volatile("s_waitcnt vmcnt(0)" ::: "memory");
    __builtin_amdgcn_s_barrier();
    __builtin_amdgcn_sched_barrier(0);

    if (kt + 2 < 32) {
      const int k0 = (kt + 2) * 32, bo = ((kt + 2) % 3) * 4096;
      gld16(ga + k0, Asb + bo + dst);
      gld16(gb + k0, Bsb + bo + dst);
    }

    const int bo = (kt % 3) * 4096;
    bf16x8 af[4], bf[2];
#pragma unroll
    for (int f = 0; f < 4; ++f) af[f] = *(const bf16x8*)&Asb[bo + aoff[f]];
#pragma unroll
    for (int g = 0; g < 2; ++g) bf[g] = *(const bf16x8*)&Bsb[bo + boff[g]];
#pragma unroll
    for (int f = 0; f < 4; ++f)
#pragma unroll
      for (int g = 0; g < 2; ++g)
        acc[f][g] = __builtin_amdgcn_mfma_f32_16x16x32_bf16(af[f], bf[g], acc[f][g], 0, 0, 0);
  }
}

// fused QKV projection: X[4096][1024]bf16 * Wt[1024][1024] -> Q/K [32][2048][64]
// bf16, and V directly into Vt' [32][64][2048] (transposed + sigma-permuted)
// via an LDS round-trip. 512 threads, 8 waves -> 6 waves/SIMD at 3 blocks/CU.
__global__ __launch_bounds__(512, 6) void k_gemm_qkv(
    const u16* __restrict__ X, const u16* __restrict__ Wq, const u16* __restrict__ Wk,
    const u16* __restrict__ Wv, u16* __restrict__ Q, u16* __restrict__ K,
    u16* __restrict__ Vt) {
  __shared__ __align__(16) u16 SH[24576];      // 48KB: staging, then C-tile
  u16* Asb = SH;
  u16* Bsb = SH + 12288;
  const int nb = blockIdx.x, mb = blockIdx.y;
  const int proj = nb >> 3, n0 = (nb & 7) * 128;
  const u16* W = proj == 0 ? Wq : proj == 1 ? Wk : Wv;
  // fold 1/sqrt(64) * log2(e) into Q so attention can use exp2 directly
  const float scl = proj == 0 ? 0.125f * 1.4426950408889634f : 1.0f;
  f32x4 acc[4][2];
  gemm8_mainloop(X, W, mb * 128, n0, Asb, Bsb, acc);

  const int tid = threadIdx.x;
  const int lane = tid & 63, wv = tid >> 6;
  const int lo = lane & 15, hi = lane >> 4;
  const int wm = (wv >> 2) * 64, wn = (wv & 3) * 32;
  const int b = (mb * 128) >> 11;              // tile never crosses batch
  const int sbase = (mb * 128) & 2047;
  const int h0 = n0 >> 6;

  // all waves done reading staging LDS before we overwrite it with C
  __syncthreads();

  if (proj == 2) {
    // V: TRANSPOSED C-tile in LDS: Ctv[n_local][s_local], padded [128][132]
    u16 (*Ctv)[132] = (u16(*)[132])SH;
#pragma unroll
    for (int f = 0; f < 4; ++f)
#pragma unroll
      for (int g = 0; g < 2; ++g)
#pragma unroll
        for (int rr = 0; rr < 4; ++rr)
          Ctv[wn + g * 16 + lo][wm + f * 16 + hi * 4 + rr] = f2bf(acc[f][g][rr]);
    __syncthreads();
    // sigma write: dst offset bp(g2) covers one full 128B line per 16 lanes
    const int g2 = tid & 15;
    const int bp = ((g2 >> 2) & 1) * 32 + ((g2 >> 1) & 1) * 16 + (g2 & 1) * 8 +
                   ((g2 >> 3) & 1) * 4;
#pragma unroll
    for (int p = 0; p < 8; ++p) {
      const int ci = p * 32 + (tid >> 4);      // 0..255
      const int blk = ci & 1, d = (ci >> 1) & 63, hl = ci >> 7;
      u64 v = *(const u64*)&Ctv[hl * 64 + d][blk * 64 + g2 * 4];
      *(u64*)&Vt[((size_t)((b * 16 + h0 + hl) * 64 + d)) * 2048 +
                 sbase + blk * 64 + bp] = v;
    }
  } else {
    u16* Dst = proj == 0 ? Q : K;
    u16 (*Ct)[132] = (u16(*)[132])SH;          // [128][132] padded, 33KB
#pragma unroll
    for (int f = 0; f < 4; ++f)
#pragma unroll
      for (int g = 0; g < 2; ++g)
#pragma unroll
        for (int rr = 0; rr < 4; ++rr)
          Ct[wm + f * 16 + hi * 4 + rr][wn + g * 16 + lo] = f2bf(acc[f][g][rr] * scl);
    __syncthreads();
    // coalesced out: 4 passes x (32 rows x 16 chunks of 8 u16)
#pragma unroll
    for (int p = 0; p < 4; ++p) {
      const int row = p * 32 + (tid >> 4);
      const int ch = tid & 15;
      const int h = h0 + (ch >> 3), d = (ch & 7) * 8;
      __align__(16) u16 o[8];
#pragma unroll
      for (int q = 0; q < 8; ++q) o[q] = Ct[row][ch * 8 + q];
      *(uint4*)&Dst[(size_t)((b * 16 + h) * 2048 + sbase + row) * 64 + d] = *(const uint4*)o;
    }
  }
}

// output projection: AO[4096][1024]bf16 * WOt -> f32 out [4096][1024].
// 512 threads, 2 waves/SIMD at the 1-block/CU grid. Epilogue goes through a
// 2-half f32 LDS round-trip so global writes are pure float4 full-line
// streams.
__global__ __launch_bounds__(512, 2) void k_gemm_out(
    const u16* __restrict__ A, const u16* __restrict__ Wt, float* __restrict__ Out) {
  __shared__ __align__(16) u16 SH[24576];      // 48KB: staging, then C halves
  u16* Asb = SH;
  u16* Bsb = SH + 12288;
  const int nb = blockIdx.x, mb = blockIdx.y;
  f32x4 acc[4][2];
  gemm8_mainloop(A, Wt, mb * 128, nb * 128, Asb, Bsb, acc);
  const int tid = threadIdx.x;
  const int lane = tid & 63, wv = tid >> 6;
  const int lo = lane & 15, hi = lane >> 4;
  const int wm = (wv >> 2) * 64, wn = (wv & 3) * 32;

  float (*Cf)[132] = (float(*)[132])SH;        // [64][132] f32, 33.8KB
#pragma unroll 1
  for (int hl = 0; hl < 2; ++hl) {
    __syncthreads();   // staging reads (hl=0) / previous half's stores (hl=1) done
    if (wm == hl * 64) {
#pragma unroll
      for (int f = 0; f < 4; ++f)
#pragma unroll
        for (int g = 0; g < 2; ++g)
#pragma unroll
          for (int rr = 0; rr < 4; ++rr)
            Cf[f * 16 + hi * 4 + rr][wn + g * 16 + lo] = acc[f][g][rr];
    }
    __syncthreads();
    // 64 rows x 32 float4 chunks = 2048 chunks; 4 per thread, coalesced
#pragma unroll
    for (int p = 0; p < 4; ++p) {
      const int c = p * 512 + tid;
      const int row = c >> 5, col4 = (c & 31) * 4;
      float4 v = *(const float4*)&Cf[row][col4];
      *(float4*)&Out[(size_t)(mb * 128 + hl * 64 + row) * 1024 + nb * 128 + col4] = v;
    }
  }
}

// ---------------------------------------------------------------- attention
DEV void qk_tile(const u16* Kc, const bf16x8 (&qf)[2], int lo, int hi, f32x4 (&sc)[4]) {
#pragma unroll
  for (int cf = 0; cf < 4; ++cf) {
    f32x4 z = {0.f, 0.f, 0.f, 0.f};
    sc[cf] = z;
#pragma unroll
    for (int kf = 0; kf < 2; ++kf) {
      int row = cf * 16 + lo;
      int blk = ((kf * 4 + hi) ^ (row & 7)) * 8;
      bf16x8 kfr = *(const bf16x8*)&Kc[row * 64 + blk];
      sc[cf] = __builtin_amdgcn_mfma_f32_16x16x32_bf16(kfr, qf[kf], sc[cf], 0, 0, 0);
    }
  }
}

// online-softmax (in-lane, defer-max) + PV for one q-tile.
// V fragments loaded FIRST so their ds_read latency hides under the softmax
// VALU chain. l_run is a PER-LANE partial (cross-lane reduce deferred to the
// epilogue — rescale factors are row-uniform so the deferred sum is exact).
DEV void sm_pv(f32x4 (&sc)[4], const u16* Vc, int lane, int lo, int hi,
               float& m_run, float& l_run, f32x4 (&ao)[4]) {
  // V fragments first (independent of softmax)
  bf16x8 vfr[4][2];
#pragma unroll
  for (int df = 0; df < 4; ++df)
#pragma unroll
    for (int kf = 0; kf < 2; ++kf) {
      int row = df * 16 + lo;
      int blk = ((kf * 4 + hi) ^ (row & 7)) * 8;
      vfr[df][kf] = *(const bf16x8*)&Vc[row * 64 + blk];
    }

  float mx0 = fmaxf(fmaxf(sc[0][0], sc[0][1]), fmaxf(sc[0][2], sc[0][3]));
  float mx1 = fmaxf(fmaxf(sc[1][0], sc[1][1]), fmaxf(sc[1][2], sc[1][3]));
  float mx2 = fmaxf(fmaxf(sc[2][0], sc[2][1]), fmaxf(sc[2][2], sc[2][3]));
  float mx3 = fmaxf(fmaxf(sc[3][0], sc[3][1]), fmaxf(sc[3][2], sc[3][3]));
  float mx = fmaxf(fmaxf(mx0, mx1), fmaxf(mx2, mx3));
  mx = fmaxf(mx, __shfl_xor(mx, 16));
  mx = fmaxf(mx, __shfl_xor(mx, 32));

  // defer-max: rescale only when the max grew by > 8 (log2 units)
  if (__any(mx > m_run + 8.0f)) {
    float mnew = fmaxf(m_run, mx);
    float sclf = __builtin_amdgcn_exp2f(m_run - mnew);
    const int base = lane & 48;
#pragma unroll
    for (int r = 0; r < 4; ++r) {
      float s_r = __shfl(sclf, base + hi * 4 + r);
#pragma unroll
      for (int df = 0; df < 4; ++df) ao[df][r] *= s_r;
    }
    l_run *= sclf;
    m_run = mnew;
  }

  // P = exp2(sc - m_run), packed in-register into PV A-fragments (sigma order)
  float pp[4];
  bf16x8 pa0, pa1;
#pragma unroll
  for (int cf = 0; cf < 4; ++cf) {
    float p0 = __builtin_amdgcn_exp2f(sc[cf][0] - m_run);
    float p1 = __builtin_amdgcn_exp2f(sc[cf][1] - m_run);
    float p2 = __builtin_amdgcn_exp2f(sc[cf][2] - m_run);
    float p3 = __builtin_amdgcn_exp2f(sc[cf][3] - m_run);
    pp[cf] = (p0 + p1) + (p2 + p3);
    bf16x8& pa = (cf & 1) ? pa1 : pa0;
    int j = (cf >> 1) * 4;
    pa[j] = (__bf16)p0; pa[j + 1] = (__bf16)p1;
    pa[j + 2] = (__bf16)p2; pa[j + 3] = (__bf16)p3;
  }
  l_run += (pp[0] + pp[1]) + (pp[2] + pp[3]);   // per-lane partial; no shuffles

  __builtin_amdgcn_s_setprio(1);
#pragma unroll
  for (int df = 0; df < 4; ++df) {
#pragma unroll
    for (int kf = 0; kf < 2; ++kf)
      ao[df] = __builtin_amdgcn_mfma_f32_16x16x32_bf16(kf == 0 ? pa0 : pa1, vfr[df][kf],
                                                       ao[df], 0, 0, 0);
  }
  __builtin_amdgcn_s_setprio(0);
}

// 8-wave (512-thread) block: one (b,h) + complementary q-tile pair (jp, 31-jp).
// Waves 0-3 own tile A=jp, waves 4-7 own tile B=31-jp; every block = 33 tile-
// computes (placement-independent balance). Counted-vmcnt pipeline: 4 LDS
// buffers, depth-3 prefetch, ONE raw s_barrier per tile, vmcnt(4) steady.
__global__ __launch_bounds__(512) void k_attn(
    const u16* __restrict__ Qg, const u16* __restrict__ Kg,
    const u16* __restrict__ Vtg, u16* __restrict__ Og) {
  __shared__ __align__(16) u16 Ks[4][64 * 64];
  __shared__ __align__(16) u16 Vs[4][64 * 64];
  const int tid = threadIdx.x, lane = tid & 63, wv = tid >> 6;
  const int lo = lane & 15, hi = lane >> 4;
  const int w4 = wv & 3, qsel = wv >> 2;

  const int flat = blockIdx.y * 16 + blockIdx.x;
  const int xcd = flat & 7, slot = flat >> 3;       // 64 slots per XCD
  const int q4 = slot >> 4, rsl = slot & 15;
  const int bh = xcd * 4 + q4;                      // 4 bh per XCD
  const int jp = (q4 & 2) ? (15 - rsl) : rsl;       // complementary pairing

  const u16* Qb = Qg + (size_t)bh * 2048 * 64;
  const u16* Kb = Kg + (size_t)bh * 2048 * 64;
  const u16* Vb = Vtg + (size_t)bh * 64 * 2048;
  const int b = bh >> 4, h = bh & 15;

  const int nta = jp + 1, ntb = 32 - jp;            // ntb >= 17
  const int q0 = (qsel ? (31 - jp) : jp) * 64;
  const int myNt = qsel ? ntb : nta;
  const int qq = q0 + w4 * 16 + lo;

  // Q fragments (scale * log2e folded in); B-operand of swapped QK^T
  bf16x8 qf[2];
#pragma unroll
  for (int kf = 0; kf < 2; ++kf)
    qf[kf] = *(const bf16x8*)&Qb[(size_t)(q0 + w4 * 16 + lo) * 64 + kf * 32 + hi * 8];

  f32x4 ao[4];
#pragma unroll
  for (int df = 0; df < 4; ++df) {
    f32x4 z = {0.f, 0.f, 0.f, 0.f};
    ao[df] = z;
  }
  float m_run = -1e30f, l_run = 0.f;

  // staging geometry: 512 chunks of 16B per 64x64 tile; 1 K + 1 V chunk/thread
  const int r0 = tid >> 3;
  const int e0 = ((tid & 7) ^ (r0 & 7)) * 8;

  // prologue: stage tiles 0,1,2 (6 VMEM ops outstanding per wave)
#pragma unroll
  for (int p = 0; p < 3; ++p) {
    gld16(Kb + (size_t)(p * 64 + r0) * 64 + e0, &Ks[p][wv * 512]);
    gld16(Vb + (size_t)r0 * 2048 + p * 64 + e0, &Vs[p][wv * 512]);
  }

#pragma unroll 1
  for (int t = 0; t < ntb; ++t) {
    // entry outstanding: loads(t),(t+1),(t+2) = 6 -> wait oldest pair done
    if (t + 2 < ntb)      asm volatile("s_waitcnt vmcnt(4)" ::: "memory");
    else if (t + 1 < ntb) asm volatile("s_waitcnt vmcnt(2)" ::: "memory");
    else                  asm volatile("s_waitcnt vmcnt(0)" ::: "memory");
    __builtin_amdgcn_s_barrier();
    __builtin_amdgcn_sched_barrier(0);

    // stage t+3 into buf (t+3)&3 == (t-1)&3 (freed by the barrier above)
    if (t + 3 < ntb) {
      const int kn = (t + 3) * 64;
      gld16(Kb + (size_t)(kn + r0) * 64 + e0, &Ks[(t + 3) & 3][wv * 512]);
      gld16(Vb + (size_t)r0 * 2048 + kn + e0, &Vs[(t + 3) & 3][wv * 512]);
    }

    if (t < myNt) {
      const u16* Kc = Ks[t & 3];
      const u16* Vc = Vs[t & 3];
      f32x4 sc[4];
      __builtin_amdgcn_s_setprio(1);
      qk_tile(Kc, qf, lo, hi, sc);
      __builtin_amdgcn_s_setprio(0);

      // causal mask: only this q-tile's diagonal (last) tile
      if (t == myNt - 1) {
        const int kv0 = t * 64;
#pragma unroll
        for (int cf = 0; cf < 4; ++cf)
#pragma unroll
          for (int r = 0; r < 4; ++r) {
            int kk = kv0 + cf * 16 + hi * 4 + r;
            if (kk > qq) sc[cf][r] = -1e30f;
          }
      }

      sm_pv(sc, Vc, lane, lo, hi, m_run, l_run, ao);
    }
  }

  // epilogue: deferred cross-lane l reduction (row lives in 4 hi-groups),
  // then per-row 1/l via shuffle. ao rows are q-offsets hi*4+r.
  float l_tot = l_run;
  l_tot += __shfl_xor(l_tot, 16);
  l_tot += __shfl_xor(l_tot, 32);
  float linv[4];
  const int base = lane & 48;
#pragma unroll
  for (int r = 0; r < 4; ++r) {
    float l_r = __shfl(l_tot, base + hi * 4 + r);
    linv[r] = 1.0f / l_r;
  }
#pragma unroll
  for (int df = 0; df < 4; ++df)
#pragma unroll
    for (int r = 0; r < 4; ++r) {
      int s = q0 + w4 * 16 + hi * 4 + r;
      int d = df * 16 + lo;
      Og[((size_t)(b * 2048 + s)) * 1024 + h * 64 + d] = f2bf(ao[df][r] * linv[r]);
    }
}

// ---------------------------------------------------------------- launch
extern "C" void kernel_launch(void* const* d_in, const int* in_sizes, int n_in,
                              void* d_out, int out_size, void* d_ws, size_t ws_size,
                              hipStream_t stream) {
  const float* x = (const float*)d_in[0];
  const float* wq = (const float*)d_in[2];
  const float* wk = (const float*)d_in[3];
  const float* wv = (const float*)d_in[4];
  const float* wo = (const float*)d_in[5];

  char* ws = (char*)d_ws;
  u16* xb  = (u16*)(ws);                                   // 8 MiB  x bf16 [4096][1024]
  u16* wqt = (u16*)(ws + 8388608);                         // 2 MiB each, [N][K] bf16
  u16* wkt = (u16*)(ws + 8388608 + 2097152);
  u16* wvt = (u16*)(ws + 8388608 + 2 * 2097152);
  u16* wot = (u16*)(ws + 8388608 + 3 * 2097152);
  u16* qb  = (u16*)(ws + 16777216);                        // [32][2048][64] bf16
  u16* kb  = (u16*)(ws + 16777216 + 8388608);
  u16* vt  = (u16*)(ws + 16777216 + 3 * 8388608);          // [32][64][2048] (sigma-permuted)
  u16* ao  = (u16*)(ws + 16777216 + 4 * 8388608);          // [4096][1024] bf16

  k_cvt<<<dim3(3072), dim3(256), 0, stream>>>(x, xb, wq, wk, wv, wo, wqt, wkt, wvt, wot);
  k_gemm_qkv<<<dim3(24, 32), dim3(512), 0, stream>>>(xb, wqt, wkt, wvt, qb, kb, vt);
  k_attn<<<dim3(16, 32), dim3(512), 0, stream>>>(qb, kb, vt, ao);
  k_gemm_out<<<dim3(8, 32), dim3(512), 0, stream>>>(ao, wot, (float*)d_out);
}